// Round 8
// baseline (826.651 us; speedup 1.0000x reference)
//
#include <hip/hip_runtime.h>
#include <stdint.h>
#include <math.h>

// Problem constants (fixed by the reference)
#define NB    32          // graphs
#define NNODE 2048        // nodes per graph
#define NT    (NB*NNODE)  // 65536 total nodes
#define EPB   16384       // edges per graph
#define ETOT  (NB*EPB)    // 524288 edges
#define DF    128         // feature dim
#define KSEL  615         // ceil(0.3*2048)
#define EMAX  512         // LDS-staged edge cap per 32-row tile (mean 256)

typedef __attribute__((ext_vector_type(8))) short bf16x8;
typedef __attribute__((ext_vector_type(4))) float f32x4;
typedef __attribute__((ext_vector_type(4))) uint32_t u32x4;

// ---- split-precision helpers: f32 ~= hi(bf16) + lo(bf16), err ~2^-17 ----
__device__ __forceinline__ unsigned short f2bf(float f){
  uint32_t u = __float_as_uint(f);
  u += 0x7FFFu + ((u>>16)&1u);                 // RNE
  return (unsigned short)(u>>16);
}
__device__ __forceinline__ void split2(float f, unsigned short& hi, unsigned short& lo){
  unsigned short h = f2bf(f);
  float fh = __uint_as_float(((uint32_t)h)<<16);
  hi = h;
  lo = f2bf(f - fh);
}
__device__ __forceinline__ uint32_t packsplit(float f){
  unsigned short h, l; split2(f, h, l);
  return ((uint32_t)h<<16) | l;
}
// monotone u32 <-> f32 (ascending u32 == ascending float over all reals)
__device__ __forceinline__ uint32_t f2mono(float f){
  uint32_t u = __float_as_uint(f);
  return (u & 0x80000000u) ? ~u : (u | 0x80000000u);
}
__device__ __forceinline__ float mono2f(uint32_t m){
  uint32_t u = (m & 0x80000000u) ? (m ^ 0x80000000u) : ~m;
  return __uint_as_float(u);
}

// ---------------- prep: per-graph CSR build + weight pack, ONE kernel ------
// blocks 0..31: graph g CSR (LDS hist -> scan -> scatter).
// blocks 32..63: packB. Bpk elem offset: ks*8192+ct*1024+part*512+lane*8+j.
__global__ __launch_bounds__(256) void k_prep(
    const int* __restrict__ esrc, const int* __restrict__ edst,
    const float* __restrict__ Wl1, const float* __restrict__ Wr1,
    const float* __restrict__ Wl2, const float* __restrict__ Wr2,
    uint32_t* __restrict__ rowptr, int* __restrict__ col,
    unsigned short* __restrict__ Bpk)
{
  __shared__ uint32_t hist[NNODE];             // 8KB
  __shared__ uint32_t wsum4[4];
  const int t = threadIdx.x;
  const int bid = blockIdx.x;

  if (bid < NB){
    const int g = bid;
    const int lane = t & 63, wid = t >> 6;
    for (int i=t; i<NNODE; i+=256) hist[i] = 0;
    __syncthreads();
    const int* ed = edst + g*EPB;
    const int* es = esrc + g*EPB;
    for (int e=t; e<EPB; e+=256) atomicAdd(&hist[ed[e]], 1u);
    __syncthreads();
    // exclusive scan of hist[2048]: 8 per thread + block scan
    uint32_t v0,v1,v2,v3,v4,v5,v6,v7;
    const int b8 = t*8;
    v0=hist[b8+0]; v1=hist[b8+1]; v2=hist[b8+2]; v3=hist[b8+3];
    v4=hist[b8+4]; v5=hist[b8+5]; v6=hist[b8+6]; v7=hist[b8+7];
    uint32_t tsum = v0+v1+v2+v3+v4+v5+v6+v7;
    uint32_t x = tsum;
    #pragma unroll
    for (int off=1; off<64; off<<=1){
      uint32_t y = __shfl_up(x, off, 64);
      if (lane >= off) x += y;
    }
    if (lane == 63) wsum4[wid] = x;
    __syncthreads();
    if (t == 0){
      uint32_t a = 0;
      #pragma unroll
      for (int w=0; w<4; ++w){ uint32_t tmp=wsum4[w]; wsum4[w]=a; a+=tmp; }
    }
    __syncthreads();
    uint32_t run = wsum4[wid] + x - tsum;      // exclusive start for this thread
    uint32_t* rp = rowptr + g*NNODE + b8;
    uint32_t h;
    h=v0; hist[b8+0]=run; rp[0]=g*EPB+run; run+=h;
    h=v1; hist[b8+1]=run; rp[1]=g*EPB+run; run+=h;
    h=v2; hist[b8+2]=run; rp[2]=g*EPB+run; run+=h;
    h=v3; hist[b8+3]=run; rp[3]=g*EPB+run; run+=h;
    h=v4; hist[b8+4]=run; rp[4]=g*EPB+run; run+=h;
    h=v5; hist[b8+5]=run; rp[5]=g*EPB+run; run+=h;
    h=v6; hist[b8+6]=run; rp[6]=g*EPB+run; run+=h;
    h=v7; hist[b8+7]=run; rp[7]=g*EPB+run; run+=h;
    if (g == 0 && t == 0) rowptr[NT] = ETOT;
    __syncthreads();
    // scatter
    for (int e=t; e<EPB; e+=256){
      int d = ed[e];
      uint32_t slot = atomicAdd(&hist[d], 1u);
      col[g*EPB + slot] = g*NNODE + es[e];
    }
  } else {
    int tt = (bid - NB)*256 + t;               // 0..8191
    int layer = tt >> 12;
    int t2 = tt & 4095;
    const float* Wl = layer ? Wl2 : Wl1;
    const float* Wr = layer ? Wr2 : Wr1;
    unsigned short* B = Bpk + (size_t)layer*65536;
    int lane = t2 & 63;
    int ct   = (t2>>6) & 7;
    int ks   = (t2>>9) & 7;
    int c  = ct*16 + (lane & 15);
    int k0 = ks*32 + ((lane>>4)<<3);
    size_t base = ((size_t)((ks*8+ct)*2)*64 + lane)*8;
    #pragma unroll
    for (int j=0;j<8;++j){
      int k = k0 + j;
      float v = (k < DF) ? Wl[c*DF + k] : Wr[c*DF + (k-DF)];
      unsigned short h, l; split2(v, h, l);
      B[base + j]       = h;
      B[base + 512 + j] = l;
    }
  }
}

// ---------------- fused SAGE layer ----------------
// 256 threads, 32 rows/block. Phase 0: stage CSR slice. Phase 1: EDGE-PARALLEL
// gather: 8 groups x 32 lanes stream independent edge-row loads (8 in flight),
// ds_add_f32 accumulate into smemA. Convert pass: smemA f32 -> *invd ->
// packed (hi<<16|lo) u32 in place. Phase 2: 4 waves (rhalf x cthalf),
// K=256: ks0-3 unpack from LDS (2 bit-ops/pair), ks4-7 own row from regs;
// 3 MFMAs (hi*hi+hi*lo+lo*hi) per (ct,ks). XCD swizzle: graph = bid&31.
template<int LAYER>
__global__ __launch_bounds__(256, 5) void k_sage(
    const float* __restrict__ Xin, const uint32_t* __restrict__ rowptr,
    const int* __restrict__ col, const unsigned short* __restrict__ Bpk,
    const float* __restrict__ bias, float* __restrict__ OUT,
    const float* __restrict__ pw, float* __restrict__ scores)
{
  __shared__ uint32_t smemA[32*132];           // 16.9KB (f32 acc -> packed u32)
  __shared__ int lcol[EMAX];                   // 2KB staged edge indices
  __shared__ uint32_t lrpl[33];                // tile-relative rowptr
  __shared__ float sp_p[32][2];
  __shared__ float sp_n2[2];
  float* smemAf = (float*)smemA;

  const int t = threadIdx.x;
  const int g = blockIdx.x & 31, jb = blockIdx.x >> 5;   // 64 blocks/graph
  const int rowBase = g*NNODE + jb*32;

  // ---- phase 0: stage CSR slice + zero accumulators ----
  const uint32_t e0 = rowptr[rowBase];
  if (t < 33) lrpl[t] = rowptr[rowBase + t] - e0;
  const int ecnt = (int)(rowptr[rowBase + 32] - e0);
  for (int i=t; i<ecnt && i<EMAX; i+=256) lcol[i] = col[e0+i];
  for (int i=t; i<32*132; i+=256) smemA[i] = 0;
  __syncthreads();

  // ---- phase 1: edge-parallel gather (8-deep independent loads) ----
  {
    const int grp = t >> 5, c = t & 31;
    const float4* X4 = (const float4*)Xin;
    auto rowOf = [&](int ii)->int{
      int n = 0;
      if (lrpl[n+16] <= (uint32_t)ii) n += 16;
      if (lrpl[n+8]  <= (uint32_t)ii) n += 8;
      if (lrpl[n+4]  <= (uint32_t)ii) n += 4;
      if (lrpl[n+2]  <= (uint32_t)ii) n += 2;
      if (lrpl[n+1]  <= (uint32_t)ii) n += 1;
      return n;
    };
    auto acc4 = [&](int n, float4 v){
      float* p = smemAf + n*132 + 4*c;
      atomicAdd(p+0, v.x); atomicAdd(p+1, v.y);
      atomicAdd(p+2, v.z); atomicAdd(p+3, v.w);
    };
    auto gather = [&](auto colAt){
      int i = grp;
      for (; i+56 < ecnt; i += 64){
        int s0=colAt(i),    s1=colAt(i+8),  s2=colAt(i+16), s3=colAt(i+24),
            s4=colAt(i+32), s5=colAt(i+40), s6=colAt(i+48), s7=colAt(i+56);
        float4 v0=X4[(size_t)s0*32+c], v1=X4[(size_t)s1*32+c],
               v2=X4[(size_t)s2*32+c], v3=X4[(size_t)s3*32+c],
               v4=X4[(size_t)s4*32+c], v5=X4[(size_t)s5*32+c],
               v6=X4[(size_t)s6*32+c], v7=X4[(size_t)s7*32+c];
        int n0=rowOf(i),    n1=rowOf(i+8),  n2=rowOf(i+16), n3=rowOf(i+24),
            n4=rowOf(i+32), n5=rowOf(i+40), n6=rowOf(i+48), n7=rowOf(i+56);
        acc4(n0,v0); acc4(n1,v1); acc4(n2,v2); acc4(n3,v3);
        acc4(n4,v4); acc4(n5,v5); acc4(n6,v6); acc4(n7,v7);
      }
      for (; i < ecnt; i += 8){
        int s = colAt(i);
        float4 v = X4[(size_t)s*32+c];
        acc4(rowOf(i), v);
      }
    };
    if (ecnt <= EMAX) gather([&](int k){ return lcol[k]; });
    else              gather([&](int k){ return col[e0+k]; });
  }

  // ---- own-row loads (issue now, consume in phase 2) ----
  const int l = t & 63, wid = t >> 6;
  const int q = l >> 4, c16 = l & 15;
  const int rhalf = wid & 1, cthalf = wid >> 1;
  const int arow = rowBase + rhalf*16 + c16;
  float4 own[8];
  #pragma unroll
  for (int ks4=0; ks4<4; ++ks4){
    const float* s = Xin + (size_t)arow*DF + ks4*32 + q*8;
    own[ks4*2]   = *(const float4*)s;
    own[ks4*2+1] = *(const float4*)(s+4);
  }
  __syncthreads();                             // all ds_adds done

  // ---- convert pass: f32 * invd -> packed (hi<<16|lo), in place ----
  {
    const int r = t >> 3, k0 = (t & 7) * 16;
    uint32_t dg = lrpl[r+1] - lrpl[r];
    float invd = 1.0f / (float)(dg ? dg : 1u);
    #pragma unroll
    for (int m=0; m<4; ++m){
      float4 f = *(float4*)&smemAf[r*132 + k0 + 4*m];
      u32x4 u;
      u.x = packsplit(f.x*invd); u.y = packsplit(f.y*invd);
      u.z = packsplit(f.z*invd); u.w = packsplit(f.w*invd);
      *(u32x4*)&smemA[r*132 + k0 + 4*m] = u;
    }
  }
  __syncthreads();

  // ---- phase 2: MFMA ----
  f32x4 acc[4];
  #pragma unroll
  for (int ct=0; ct<4; ++ct) acc[ct] = (f32x4){0.f,0.f,0.f,0.f};

  #pragma unroll
  for (int ks=0; ks<4; ++ks){                  // agg half: unpack from LDS
    const uint32_t* pa = smemA + (rhalf*16 + c16)*132 + ks*32 + q*8;
    uint4 ua = *(const uint4*)pa;
    uint4 ub = *(const uint4*)(pa+4);
    u32x4 hh, ll;
    hh.x = (ua.y & 0xFFFF0000u) | (ua.x >> 16);
    ll.x = (ua.y << 16)         | (ua.x & 0xFFFFu);
    hh.y = (ua.w & 0xFFFF0000u) | (ua.z >> 16);
    ll.y = (ua.w << 16)         | (ua.z & 0xFFFFu);
    hh.z = (ub.y & 0xFFFF0000u) | (ub.x >> 16);
    ll.z = (ub.y << 16)         | (ub.x & 0xFFFFu);
    hh.w = (ub.w & 0xFFFF0000u) | (ub.z >> 16);
    ll.w = (ub.w << 16)         | (ub.z & 0xFFFFu);
    bf16x8 ahi = __builtin_bit_cast(bf16x8, hh);
    bf16x8 alo = __builtin_bit_cast(bf16x8, ll);
    const unsigned short* bp = Bpk + (size_t)ks*8192 + (size_t)cthalf*4096 + l*8;
    #pragma unroll
    for (int ct=0; ct<4; ++ct){
      bf16x8 bhi = *(const bf16x8*)(bp + ct*1024);
      bf16x8 blo = *(const bf16x8*)(bp + ct*1024 + 512);
      acc[ct] = __builtin_amdgcn_mfma_f32_16x16x32_bf16(ahi, bhi, acc[ct], 0,0,0);
      acc[ct] = __builtin_amdgcn_mfma_f32_16x16x32_bf16(ahi, blo, acc[ct], 0,0,0);
      acc[ct] = __builtin_amdgcn_mfma_f32_16x16x32_bf16(alo, bhi, acc[ct], 0,0,0);
    }
  }
  #pragma unroll
  for (int ks=4; ks<8; ++ks){                  // own half: split from regs
    float4 A0 = own[(ks-4)*2], A1 = own[(ks-4)*2+1];
    float v[8] = {A0.x,A0.y,A0.z,A0.w,A1.x,A1.y,A1.z,A1.w};
    bf16x8 ahi, alo;
    #pragma unroll
    for (int j=0;j<8;++j){
      unsigned short h, lo_; split2(v[j], h, lo_);
      ahi[j] = (short)h; alo[j] = (short)lo_;
    }
    const unsigned short* bp = Bpk + (size_t)ks*8192 + (size_t)cthalf*4096 + l*8;
    #pragma unroll
    for (int ct=0; ct<4; ++ct){
      bf16x8 bhi = *(const bf16x8*)(bp + ct*1024);
      bf16x8 blo = *(const bf16x8*)(bp + ct*1024 + 512);
      acc[ct] = __builtin_amdgcn_mfma_f32_16x16x32_bf16(ahi, bhi, acc[ct], 0,0,0);
      acc[ct] = __builtin_amdgcn_mfma_f32_16x16x32_bf16(ahi, blo, acc[ct], 0,0,0);
      acc[ct] = __builtin_amdgcn_mfma_f32_16x16x32_bf16(alo, bhi, acc[ct], 0,0,0);
    }
  }

  // ---- epilogue ----
  const int rowOut = rowBase + rhalf*16;
  if constexpr (LAYER==1){
    #pragma unroll
    for (int ct=0; ct<4; ++ct){
      int c = cthalf*64 + ct*16 + c16;
      float bv = bias[c];
      #pragma unroll
      for (int r=0; r<4; ++r){
        int grow = rowOut + q*4 + r;
        OUT[(size_t)grow*DF + c] = fmaxf(acc[ct][r] + bv, 0.f);
      }
    }
  } else {
    float ov[4][4];
    float pwv[4];
    float n2 = 0.f;
    #pragma unroll
    for (int ct=0; ct<4; ++ct){
      pwv[ct] = pw[cthalf*64 + ct*16 + c16];
      n2 += pwv[ct]*pwv[ct];
    }
    n2 += __shfl_xor(n2,8,16); n2 += __shfl_xor(n2,4,16);
    n2 += __shfl_xor(n2,2,16); n2 += __shfl_xor(n2,1,16);
    if (l == 0) sp_n2[cthalf] = n2;
    #pragma unroll
    for (int ct=0; ct<4; ++ct){
      int c = cthalf*64 + ct*16 + c16;
      float bv = bias[c];
      #pragma unroll
      for (int r=0; r<4; ++r){
        int grow = rowOut + q*4 + r;
        float o = fmaxf(acc[ct][r] + bv, 0.f);
        OUT[(size_t)grow*DF + c] = o;
        ov[ct][r] = o;
      }
    }
    #pragma unroll
    for (int r=0; r<4; ++r){
      float p = 0.f;
      #pragma unroll
      for (int ct=0; ct<4; ++ct) p += ov[ct][r]*pwv[ct];
      p += __shfl_xor(p,8,16); p += __shfl_xor(p,4,16);
      p += __shfl_xor(p,2,16); p += __shfl_xor(p,1,16);
      if (c16 == 0) sp_p[rhalf*16 + q*4 + r][cthalf] = p;
    }
    __syncthreads();
    if (t < 32){
      float p = sp_p[t][0] + sp_p[t][1];
      float nrm = sqrtf(sp_n2[0] + sp_n2[1]);
      scores[rowBase + t] = tanhf(p/nrm);
    }
  }
}

// ---------------- top-k via radix-select + pool + classifier ---------------
__global__ __launch_bounds__(1024) void k_topk(
    const float* __restrict__ scores, const float* __restrict__ H,
    const float* __restrict__ Wc1, const float* __restrict__ bc1,
    const float* __restrict__ Wc2, const float* __restrict__ bc2,
    float* __restrict__ out)
{
  __shared__ uint32_t keys[NNODE];            // 8KB monotone keys
  __shared__ uint32_t hist[64];
  __shared__ uint32_t wsum[16];               // block-scan wave sums
  __shared__ uint32_t sh_b, sh_rank, sh_cnt;
  __shared__ unsigned short selidx[KSEL+1];
  __shared__ float selval[KSEL+1];
  __shared__ float part[8*DF];
  __shared__ float emb[DF];
  __shared__ float hred[DF];

  const int t = threadIdx.x; const int b = blockIdx.x;
  const int lane = t & 63, wid = t >> 6;
  const float* sc = scores + b*NNODE;

  for (int i=t; i<NNODE; i+=1024) keys[i] = f2mono(sc[i]);
  __syncthreads();

  // ---- radix select: find threshold key T = 615th largest ----
  uint32_t prefix = 0, prefmask = 0, rank = KSEL, cntT = 0;
  #pragma unroll
  for (int lev=0; lev<6; ++lev){
    const int shift = (lev<5) ? (26 - 6*lev) : 0;
    const uint32_t bmask = (lev<5) ? 63u : 3u;
    if (t < 64) hist[t] = 0;
    __syncthreads();
    for (int i=t; i<NNODE; i+=1024){
      uint32_t k = keys[i];
      if ((k & prefmask) == prefix) atomicAdd(&hist[(k>>shift)&bmask], 1u);
    }
    __syncthreads();
    if (t < 64){
      uint32_t x = hist[t];
      #pragma unroll
      for (int off=1; off<64; off<<=1){        // inclusive suffix sum
        uint32_t y = __shfl_down(x, off, 64);
        if (t + off < 64) x += y;
      }
      uint32_t above = __shfl_down(x, 1, 64);
      if (t == 63) above = 0;
      if (above < rank && rank <= x){
        sh_b = (uint32_t)t; sh_rank = rank - above; sh_cnt = x - above;
      }
    }
    __syncthreads();
    prefix |= (sh_b << shift);
    prefmask |= (bmask << shift);
    rank = sh_rank; cntT = sh_cnt;
    __syncthreads();
  }
  const uint32_t T = prefix;
  const uint32_t m = rank;

  // ---- selection + compaction (block scans, shfl-based) ----
  uint32_t k0 = keys[2*t], k1 = keys[2*t+1];
  uint32_t eq0 = (k0 == T), eq1 = (k1 == T);
  uint32_t eqr0 = 0, eqr1 = 0;

  if (m != cntT){
    uint32_t v = eq0 + eq1, x = v;
    #pragma unroll
    for (int off=1; off<64; off<<=1){
      uint32_t y = __shfl_up(x, off, 64);
      if (lane >= off) x += y;
    }
    if (lane == 63) wsum[wid] = x;
    __syncthreads();
    if (wid == 0){
      uint32_t s = (lane < 16) ? wsum[lane] : 0;
      #pragma unroll
      for (int off=1; off<16; off<<=1){
        uint32_t y = __shfl_up(s, off, 64);
        if (lane >= off) s += y;
      }
      if (lane < 16) wsum[lane] = s;
    }
    __syncthreads();
    uint32_t excl = (wid ? wsum[wid-1] : 0) + x - v;
    eqr0 = excl; eqr1 = excl + eq0;
    __syncthreads();
  }

  uint32_t sel0 = (k0 > T) || (eq0 && eqr0 < m);
  uint32_t sel1 = (k1 > T) || (eq1 && eqr1 < m);
  {
    uint32_t v = sel0 + sel1, x = v;
    #pragma unroll
    for (int off=1; off<64; off<<=1){
      uint32_t y = __shfl_up(x, off, 64);
      if (lane >= off) x += y;
    }
    if (lane == 63) wsum[wid] = x;
    __syncthreads();
    if (wid == 0){
      uint32_t s = (lane < 16) ? wsum[lane] : 0;
      #pragma unroll
      for (int off=1; off<16; off<<=1){
        uint32_t y = __shfl_up(s, off, 64);
        if (lane >= off) s += y;
      }
      if (lane < 16) wsum[lane] = s;
    }
    __syncthreads();
    uint32_t excl = (wid ? wsum[wid-1] : 0) + x - v;
    if (sel0){ selidx[excl] = (unsigned short)(2*t);   selval[excl] = mono2f(k0); }
    if (sel1){ selidx[excl+sel0] = (unsigned short)(2*t+1); selval[excl+sel0] = mono2f(k1); }
  }
  __syncthreads();

  // ---- gated mean over the 615 selected rows (4-deep unrolled gather) ----
  const int pg = t >> 7, f = t & (DF-1);
  const float* Hb = H + (size_t)b*NNODE*DF;
  float accv = 0.f;
  int s2 = pg;
  for (; s2+24 < KSEL; s2 += 32){
    int i0=selidx[s2], i1=selidx[s2+8], i2=selidx[s2+16], i3=selidx[s2+24];
    float w0=selval[s2], w1=selval[s2+8], w2=selval[s2+16], w3=selval[s2+24];
    float v0=Hb[(size_t)i0*DF+f], v1=Hb[(size_t)i1*DF+f],
          v2=Hb[(size_t)i2*DF+f], v3=Hb[(size_t)i3*DF+f];
    accv += w0*v0 + w1*v1 + w2*v2 + w3*v3;
  }
  for (; s2<KSEL; s2+=8) accv += selval[s2]*Hb[(size_t)selidx[s2]*DF+f];
  part[pg*DF + f] = accv;
  __syncthreads();
  if (t < DF){
    float e = 0.f;
    for (int g2=0; g2<8; ++g2) e += part[g2*DF + t];
    emb[t] = e / (float)KSEL;
  }
  __syncthreads();
  if (t < DF){
    float hv = bc1[t];
    const float* wr = Wc1 + t*DF;
    for (int f2=0; f2<DF; ++f2) hv = fmaf(emb[f2], wr[f2], hv);
    hred[t] = fmaxf(hv, 0.f) * Wc2[t];
  }
  __syncthreads();
  if (t == 0){
    float o = bc2[0];
    for (int c2=0; c2<DF; ++c2) o += hred[c2];
    out[b] = o;
  }
}

// ---------------- launch ----------------
extern "C" void kernel_launch(void* const* d_in, const int* in_sizes, int n_in,
                              void* d_out, int out_size, void* d_ws, size_t ws_size,
                              hipStream_t stream)
{
  (void)in_sizes; (void)n_in; (void)out_size; (void)ws_size;
  const float* x   = (const float*)d_in[0];
  const int* esrc  = (const int*)d_in[1];
  const int* edst  = (const int*)d_in[2];
  const float* Wl1 = (const float*)d_in[3];
  const float* bl1 = (const float*)d_in[4];
  const float* Wr1 = (const float*)d_in[5];
  const float* Wl2 = (const float*)d_in[6];
  const float* bl2 = (const float*)d_in[7];
  const float* Wr2 = (const float*)d_in[8];
  const float* pw  = (const float*)d_in[9];
  const float* Wc1 = (const float*)d_in[10];
  const float* bc1 = (const float*)d_in[11];
  const float* Wc2 = (const float*)d_in[12];
  const float* bc2 = (const float*)d_in[13];
  float* out = (float*)d_out;

  char* ws = (char*)d_ws;                       // ~70 MB used
  float*    H1     = (float*)   (ws + 0);          // 32MB
  float*    H2     = (float*)   (ws + 33554432);   // 32MB
  uint32_t* rowptr = (uint32_t*)(ws + 67108864);   // 65537 u32 (pad 262400)
  int*      col    = (int*)     (ws + 67371264);   // 2MB
  float*    scores = (float*)   (ws + 69468416);   // 256KB
  unsigned short* Bpk = (unsigned short*)(ws + 69730560); // 256KB (2 layers)

  // one prep kernel: per-graph CSR (blocks 0..31) + weight pack (32..63)
  k_prep<<<64, 256, 0, stream>>>(esrc, edst, Wl1, Wr1, Wl2, Wr2,
                                 rowptr, col, Bpk);

  // fused layers: edge-parallel gather + mean + GEMM per block
  k_sage<1><<<NT/32, 256, 0, stream>>>(x,  rowptr, col, Bpk,         bl1,
                                       H1, nullptr, nullptr);
  k_sage<2><<<NT/32, 256, 0, stream>>>(H1, rowptr, col, Bpk + 65536, bl2,
                                       H2, pw, scores);

  k_topk<<<NB, 1024, 0, stream>>>(scores, H2, Wc1, bc1, Wc2, bc2, out);
}

// Round 9
// 165.844 us; speedup vs baseline: 4.9845x; 4.9845x over previous
//
#include <hip/hip_runtime.h>
#include <stdint.h>
#include <math.h>

// Problem constants (fixed by the reference)
#define NB    32          // graphs
#define NNODE 2048        // nodes per graph
#define NT    (NB*NNODE)  // 65536 total nodes
#define EPB   16384       // edges per graph
#define ETOT  (NB*EPB)    // 524288 edges
#define DF    128         // feature dim
#define KSEL  615         // ceil(0.3*2048)
#define EMAX  512         // LDS-staged edge cap per 32-row tile (mean 256)

typedef __attribute__((ext_vector_type(8))) short bf16x8;
typedef __attribute__((ext_vector_type(4))) float f32x4;

// ---- split-precision helpers: f32 ~= hi(bf16) + lo(bf16), err ~2^-17 ----
__device__ __forceinline__ unsigned short f2bf(float f){
  uint32_t u = __float_as_uint(f);
  u += 0x7FFFu + ((u>>16)&1u);                 // RNE
  return (unsigned short)(u>>16);
}
__device__ __forceinline__ void split2(float f, unsigned short& hi, unsigned short& lo){
  unsigned short h = f2bf(f);
  float fh = __uint_as_float(((uint32_t)h)<<16);
  hi = h;
  lo = f2bf(f - fh);
}
// monotone u32 <-> f32 (ascending u32 == ascending float over all reals)
__device__ __forceinline__ uint32_t f2mono(float f){
  uint32_t u = __float_as_uint(f);
  return (u & 0x80000000u) ? ~u : (u | 0x80000000u);
}
__device__ __forceinline__ float mono2f(uint32_t m){
  uint32_t u = (m & 0x80000000u) ? (m ^ 0x80000000u) : ~m;
  return __uint_as_float(u);
}
// nontemporal 16B load/store (L1 bypass hint — gather rows have no L1 reuse)
__device__ __forceinline__ f32x4 ntload4(const float* p){
  return __builtin_nontemporal_load((const f32x4*)p);
}
__device__ __forceinline__ void ntstore(float v, float* p){
  __builtin_nontemporal_store(v, p);
}

// ---------------- prep: per-graph CSR build + weight pack, ONE kernel ------
// blocks 0..31: graph g CSR (LDS hist -> scan -> scatter).
// blocks 32..63: packB. Bpk elem offset: ks*8192+ct*1024+part*512+lane*8+j.
__global__ __launch_bounds__(256) void k_prep(
    const int* __restrict__ esrc, const int* __restrict__ edst,
    const float* __restrict__ Wl1, const float* __restrict__ Wr1,
    const float* __restrict__ Wl2, const float* __restrict__ Wr2,
    uint32_t* __restrict__ rowptr, int* __restrict__ col,
    unsigned short* __restrict__ Bpk)
{
  __shared__ uint32_t hist[NNODE];             // 8KB
  __shared__ uint32_t wsum4[4];
  const int t = threadIdx.x;
  const int bid = blockIdx.x;

  if (bid < NB){
    const int g = bid;
    const int lane = t & 63, wid = t >> 6;
    for (int i=t; i<NNODE; i+=256) hist[i] = 0;
    __syncthreads();
    const int* ed = edst + g*EPB;
    const int* es = esrc + g*EPB;
    for (int e=t; e<EPB; e+=256) atomicAdd(&hist[ed[e]], 1u);
    __syncthreads();
    // exclusive scan of hist[2048]: 8 per thread + block scan
    uint32_t v0,v1,v2,v3,v4,v5,v6,v7;
    const int b8 = t*8;
    v0=hist[b8+0]; v1=hist[b8+1]; v2=hist[b8+2]; v3=hist[b8+3];
    v4=hist[b8+4]; v5=hist[b8+5]; v6=hist[b8+6]; v7=hist[b8+7];
    uint32_t tsum = v0+v1+v2+v3+v4+v5+v6+v7;
    uint32_t x = tsum;
    #pragma unroll
    for (int off=1; off<64; off<<=1){
      uint32_t y = __shfl_up(x, off, 64);
      if (lane >= off) x += y;
    }
    if (lane == 63) wsum4[wid] = x;
    __syncthreads();
    if (t == 0){
      uint32_t a = 0;
      #pragma unroll
      for (int w=0; w<4; ++w){ uint32_t tmp=wsum4[w]; wsum4[w]=a; a+=tmp; }
    }
    __syncthreads();
    uint32_t run = wsum4[wid] + x - tsum;      // exclusive start for this thread
    uint32_t* rp = rowptr + g*NNODE + b8;
    uint32_t h;
    h=v0; hist[b8+0]=run; rp[0]=g*EPB+run; run+=h;
    h=v1; hist[b8+1]=run; rp[1]=g*EPB+run; run+=h;
    h=v2; hist[b8+2]=run; rp[2]=g*EPB+run; run+=h;
    h=v3; hist[b8+3]=run; rp[3]=g*EPB+run; run+=h;
    h=v4; hist[b8+4]=run; rp[4]=g*EPB+run; run+=h;
    h=v5; hist[b8+5]=run; rp[5]=g*EPB+run; run+=h;
    h=v6; hist[b8+6]=run; rp[6]=g*EPB+run; run+=h;
    h=v7; hist[b8+7]=run; rp[7]=g*EPB+run; run+=h;
    if (g == 0 && t == 0) rowptr[NT] = ETOT;
    __syncthreads();
    // scatter
    for (int e=t; e<EPB; e+=256){
      int d = ed[e];
      uint32_t slot = atomicAdd(&hist[d], 1u);
      col[g*EPB + slot] = g*NNODE + es[e];
    }
  } else {
    int tt = (bid - NB)*256 + t;               // 0..8191
    int layer = tt >> 12;
    int t2 = tt & 4095;
    const float* Wl = layer ? Wl2 : Wl1;
    const float* Wr = layer ? Wr2 : Wr1;
    unsigned short* B = Bpk + (size_t)layer*65536;
    int lane = t2 & 63;
    int ct   = (t2>>6) & 7;
    int ks   = (t2>>9) & 7;
    int c  = ct*16 + (lane & 15);
    int k0 = ks*32 + ((lane>>4)<<3);
    size_t base = ((size_t)((ks*8+ct)*2)*64 + lane)*8;
    #pragma unroll
    for (int j=0;j<8;++j){
      int k = k0 + j;
      float v = (k < DF) ? Wl[c*DF + k] : Wr[c*DF + (k-DF)];
      unsigned short h, l; split2(v, h, l);
      B[base + j]       = h;
      B[base + 512 + j] = l;
    }
  }
}

// ---------------- fused SAGE layer: agg(gather+mean) + split-bf16 MFMA -----
// 128 threads, 32 rows/block (round-6 structure). Phase 0: stage CSR slice to
// LDS + prefetch own x-row (NT). Phase 1: 4 groups x 32 lanes gather neighbor
// rows (8-deep ILP, NT loads, LDS indices) -> mean -> LDS [32][132]. Phase 2:
// 2 waves x 16 rows, K=256 (ks0-3 agg from LDS, ks4-7 own row from regs),
// 3 MFMAs (hi*hi+hi*lo+lo*hi) per (ct,ks). NT stores for OUT.
// XCD swizzle: graph = bid&31.
template<int LAYER>
__global__ __launch_bounds__(128, 4) void k_sage(
    const float* __restrict__ Xin, const uint32_t* __restrict__ rowptr,
    const int* __restrict__ col, const unsigned short* __restrict__ Bpk,
    const float* __restrict__ bias, float* __restrict__ OUT,
    const float* __restrict__ pw, float* __restrict__ scores)
{
  __shared__ float smemA[32][132];             // 16.9KB, +4 float pad per row
  __shared__ int lcol[EMAX];                   // 2KB staged edge indices
  __shared__ uint32_t lrp[33];

  const int t = threadIdx.x;
  const int g = blockIdx.x & 31, jb = blockIdx.x >> 5;   // 64 blocks/graph
  const int rowBase = g*NNODE + jb*32;

  // ---- phase 0: stage CSR slice + prefetch own row ----
  if (t < 33) lrp[t] = rowptr[rowBase + t];
  const uint32_t e0 = rowptr[rowBase];
  const int ecnt = (int)(rowptr[rowBase + 32] - e0);
  for (int i=t; i<ecnt && i<EMAX; i+=128) lcol[i] = col[e0+i];

  const int l = t & 63, wid = t >> 6;
  const int q = l >> 4, c16 = l & 15;
  const int arow = rowBase + wid*16 + c16;
  f32x4 own[8];                                // own row ks4..7, consumed ph2
  #pragma unroll
  for (int ks4=0; ks4<4; ++ks4){
    const float* s = Xin + (size_t)arow*DF + ks4*32 + q*8;
    own[ks4*2]   = ntload4(s);
    own[ks4*2+1] = ntload4(s+4);
  }
  __syncthreads();

  // ---- phase 1: gather + mean (8-deep unrolled, NT loads, LDS indices) ----
  {
    const int grp = t >> 5, c = t & 31;
    auto gather = [&](auto colAt){
      for (int n=grp; n<32; n+=4){
        uint32_t b = lrp[n] - e0, e = lrp[n+1] - e0;
        f32x4 a = {0.f,0.f,0.f,0.f};
        uint32_t k = b;
        for (; k+8<=e; k+=8){
          int s0=colAt(k),  s1=colAt(k+1), s2=colAt(k+2), s3=colAt(k+3),
              s4=colAt(k+4),s5=colAt(k+5), s6=colAt(k+6), s7=colAt(k+7);
          f32x4 v0=ntload4(Xin+(size_t)s0*DF+4*c), v1=ntload4(Xin+(size_t)s1*DF+4*c),
                v2=ntload4(Xin+(size_t)s2*DF+4*c), v3=ntload4(Xin+(size_t)s3*DF+4*c),
                v4=ntload4(Xin+(size_t)s4*DF+4*c), v5=ntload4(Xin+(size_t)s5*DF+4*c),
                v6=ntload4(Xin+(size_t)s6*DF+4*c), v7=ntload4(Xin+(size_t)s7*DF+4*c);
          a += ((v0+v1)+(v2+v3)) + ((v4+v5)+(v6+v7));
        }
        for (; k+4<=e; k+=4){
          int s0=colAt(k), s1=colAt(k+1), s2=colAt(k+2), s3=colAt(k+3);
          f32x4 v0=ntload4(Xin+(size_t)s0*DF+4*c), v1=ntload4(Xin+(size_t)s1*DF+4*c),
                v2=ntload4(Xin+(size_t)s2*DF+4*c), v3=ntload4(Xin+(size_t)s3*DF+4*c);
          a += (v0+v1)+(v2+v3);
        }
        for (; k<e; ++k){
          a += ntload4(Xin+(size_t)colAt(k)*DF+4*c);
        }
        float invd = 1.0f / (float)((e>b)?(e-b):1u);
        *(f32x4*)&smemA[n][4*c] = a * invd;
      }
    };
    if (ecnt <= EMAX) gather([&](uint32_t k){ return lcol[k]; });
    else              gather([&](uint32_t k){ return col[e0+k]; });
  }
  __syncthreads();

  // ---- phase 2: MFMA ----
  f32x4 acc[8];
  #pragma unroll
  for (int ct=0; ct<8; ++ct) acc[ct] = (f32x4){0.f,0.f,0.f,0.f};

  #pragma unroll
  for (int ks=0; ks<8; ++ks){
    f32x4 A0, A1;
    if (ks < 4){
      const float* s = &smemA[wid*16 + c16][ks*32 + q*8];
      A0 = *(const f32x4*)s; A1 = *(const f32x4*)(s+4);
    } else {
      A0 = own[(ks-4)*2]; A1 = own[(ks-4)*2+1];
    }
    float v[8] = {A0.x,A0.y,A0.z,A0.w,A1.x,A1.y,A1.z,A1.w};
    bf16x8 ahi, alo;
    #pragma unroll
    for (int j=0;j<8;++j){
      unsigned short h, lo_; split2(v[j], h, lo_);
      ahi[j] = (short)h; alo[j] = (short)lo_;
    }
    const unsigned short* bp = Bpk + (size_t)ks*8192 + l*8;
    #pragma unroll
    for (int ct=0; ct<8; ++ct){
      bf16x8 bhi = *(const bf16x8*)(bp + ct*1024);
      bf16x8 blo = *(const bf16x8*)(bp + ct*1024 + 512);
      acc[ct] = __builtin_amdgcn_mfma_f32_16x16x32_bf16(ahi, bhi, acc[ct], 0,0,0);
      acc[ct] = __builtin_amdgcn_mfma_f32_16x16x32_bf16(ahi, blo, acc[ct], 0,0,0);
      acc[ct] = __builtin_amdgcn_mfma_f32_16x16x32_bf16(alo, bhi, acc[ct], 0,0,0);
    }
  }

  // ---- epilogue (NT stores) ----
  const int rowOut = rowBase + wid*16;
  if constexpr (LAYER==1){
    #pragma unroll
    for (int ct=0; ct<8; ++ct){
      int c = ct*16 + c16;
      float bv = bias[c];
      #pragma unroll
      for (int r=0; r<4; ++r){
        int grow = rowOut + q*4 + r;
        ntstore(fmaxf(acc[ct][r] + bv, 0.f), &OUT[(size_t)grow*DF + c]);
      }
    }
  } else {
    float ov[8][4];
    float pwv[8];
    float n2 = 0.f;
    #pragma unroll
    for (int ct=0; ct<8; ++ct){ pwv[ct] = pw[ct*16 + c16]; n2 += pwv[ct]*pwv[ct]; }
    n2 += __shfl_xor(n2,8,16); n2 += __shfl_xor(n2,4,16);
    n2 += __shfl_xor(n2,2,16); n2 += __shfl_xor(n2,1,16);
    float nrm = sqrtf(n2);
    #pragma unroll
    for (int ct=0; ct<8; ++ct){
      int c = ct*16 + c16;
      float bv = bias[c];
      #pragma unroll
      for (int r=0; r<4; ++r){
        int grow = rowOut + q*4 + r;
        float o = fmaxf(acc[ct][r] + bv, 0.f);
        ntstore(o, &OUT[(size_t)grow*DF + c]);
        ov[ct][r] = o;
      }
    }
    #pragma unroll
    for (int r=0; r<4; ++r){
      float p = 0.f;
      #pragma unroll
      for (int ct=0; ct<8; ++ct) p += ov[ct][r]*pwv[ct];
      p += __shfl_xor(p,8,16); p += __shfl_xor(p,4,16);
      p += __shfl_xor(p,2,16); p += __shfl_xor(p,1,16);
      if (c16 == 0) scores[rowOut + q*4 + r] = tanhf(p/nrm);
    }
  }
}

// ---------------- top-k via radix-select + pool + classifier ---------------
__global__ __launch_bounds__(1024) void k_topk(
    const float* __restrict__ scores, const float* __restrict__ H,
    const float* __restrict__ Wc1, const float* __restrict__ bc1,
    const float* __restrict__ Wc2, const float* __restrict__ bc2,
    float* __restrict__ out)
{
  __shared__ uint32_t keys[NNODE];            // 8KB monotone keys
  __shared__ uint32_t hist[64];
  __shared__ uint32_t wsum[16];               // block-scan wave sums
  __shared__ uint32_t sh_b, sh_rank, sh_cnt;
  __shared__ unsigned short selidx[KSEL+1];
  __shared__ float selval[KSEL+1];
  __shared__ float part[8*DF];
  __shared__ float emb[DF];
  __shared__ float hred[DF];

  const int t = threadIdx.x; const int b = blockIdx.x;
  const int lane = t & 63, wid = t >> 6;
  const float* sc = scores + b*NNODE;

  for (int i=t; i<NNODE; i+=1024) keys[i] = f2mono(sc[i]);
  __syncthreads();

  // ---- radix select: find threshold key T = 615th largest ----
  uint32_t prefix = 0, prefmask = 0, rank = KSEL, cntT = 0;
  #pragma unroll
  for (int lev=0; lev<6; ++lev){
    const int shift = (lev<5) ? (26 - 6*lev) : 0;
    const uint32_t bmask = (lev<5) ? 63u : 3u;
    if (t < 64) hist[t] = 0;
    __syncthreads();
    for (int i=t; i<NNODE; i+=1024){
      uint32_t k = keys[i];
      if ((k & prefmask) == prefix) atomicAdd(&hist[(k>>shift)&bmask], 1u);
    }
    __syncthreads();
    if (t < 64){
      uint32_t x = hist[t];
      #pragma unroll
      for (int off=1; off<64; off<<=1){        // inclusive suffix sum
        uint32_t y = __shfl_down(x, off, 64);
        if (t + off < 64) x += y;
      }
      uint32_t above = __shfl_down(x, 1, 64);
      if (t == 63) above = 0;
      if (above < rank && rank <= x){
        sh_b = (uint32_t)t; sh_rank = rank - above; sh_cnt = x - above;
      }
    }
    __syncthreads();
    prefix |= (sh_b << shift);
    prefmask |= (bmask << shift);
    rank = sh_rank; cntT = sh_cnt;
    __syncthreads();
  }
  const uint32_t T = prefix;
  const uint32_t m = rank;

  // ---- selection + compaction (block scans, shfl-based) ----
  uint32_t k0 = keys[2*t], k1 = keys[2*t+1];
  uint32_t eq0 = (k0 == T), eq1 = (k1 == T);
  uint32_t eqr0 = 0, eqr1 = 0;

  if (m != cntT){
    uint32_t v = eq0 + eq1, x = v;
    #pragma unroll
    for (int off=1; off<64; off<<=1){
      uint32_t y = __shfl_up(x, off, 64);
      if (lane >= off) x += y;
    }
    if (lane == 63) wsum[wid] = x;
    __syncthreads();
    if (wid == 0){
      uint32_t s = (lane < 16) ? wsum[lane] : 0;
      #pragma unroll
      for (int off=1; off<16; off<<=1){
        uint32_t y = __shfl_up(s, off, 64);
        if (lane >= off) s += y;
      }
      if (lane < 16) wsum[lane] = s;
    }
    __syncthreads();
    uint32_t excl = (wid ? wsum[wid-1] : 0) + x - v;
    eqr0 = excl; eqr1 = excl + eq0;
    __syncthreads();
  }

  uint32_t sel0 = (k0 > T) || (eq0 && eqr0 < m);
  uint32_t sel1 = (k1 > T) || (eq1 && eqr1 < m);
  {
    uint32_t v = sel0 + sel1, x = v;
    #pragma unroll
    for (int off=1; off<64; off<<=1){
      uint32_t y = __shfl_up(x, off, 64);
      if (lane >= off) x += y;
    }
    if (lane == 63) wsum[wid] = x;
    __syncthreads();
    if (wid == 0){
      uint32_t s = (lane < 16) ? wsum[lane] : 0;
      #pragma unroll
      for (int off=1; off<16; off<<=1){
        uint32_t y = __shfl_up(s, off, 64);
        if (lane >= off) s += y;
      }
      if (lane < 16) wsum[lane] = s;
    }
    __syncthreads();
    uint32_t excl = (wid ? wsum[wid-1] : 0) + x - v;
    if (sel0){ selidx[excl] = (unsigned short)(2*t);   selval[excl] = mono2f(k0); }
    if (sel1){ selidx[excl+sel0] = (unsigned short)(2*t+1); selval[excl+sel0] = mono2f(k1); }
  }
  __syncthreads();

  // ---- gated mean over the 615 selected rows (4-deep unrolled gather) ----
  const int pg = t >> 7, f = t & (DF-1);
  const float* Hb = H + (size_t)b*NNODE*DF;
  float accv = 0.f;
  int s2 = pg;
  for (; s2+24 < KSEL; s2 += 32){
    int i0=selidx[s2], i1=selidx[s2+8], i2=selidx[s2+16], i3=selidx[s2+24];
    float w0=selval[s2], w1=selval[s2+8], w2=selval[s2+16], w3=selval[s2+24];
    float v0=Hb[(size_t)i0*DF+f], v1=Hb[(size_t)i1*DF+f],
          v2=Hb[(size_t)i2*DF+f], v3=Hb[(size_t)i3*DF+f];
    accv += w0*v0 + w1*v1 + w2*v2 + w3*v3;
  }
  for (; s2<KSEL; s2+=8) accv += selval[s2]*Hb[(size_t)selidx[s2]*DF+f];
  part[pg*DF + f] = accv;
  __syncthreads();
  if (t < DF){
    float e = 0.f;
    for (int g2=0; g2<8; ++g2) e += part[g2*DF + t];
    emb[t] = e / (float)KSEL;
  }
  __syncthreads();
  if (t < DF){
    float hv = bc1[t];
    const float* wr = Wc1 + t*DF;
    for (int f2=0; f2<DF; ++f2) hv = fmaf(emb[f2], wr[f2], hv);
    hred[t] = fmaxf(hv, 0.f) * Wc2[t];
  }
  __syncthreads();
  if (t == 0){
    float o = bc2[0];
    for (int c2=0; c2<DF; ++c2) o += hred[c2];
    out[b] = o;
  }
}

// ---------------- launch ----------------
extern "C" void kernel_launch(void* const* d_in, const int* in_sizes, int n_in,
                              void* d_out, int out_size, void* d_ws, size_t ws_size,
                              hipStream_t stream)
{
  (void)in_sizes; (void)n_in; (void)out_size; (void)ws_size;
  const float* x   = (const float*)d_in[0];
  const int* esrc  = (const int*)d_in[1];
  const int* edst  = (const int*)d_in[2];
  const float* Wl1 = (const float*)d_in[3];
  const float* bl1 = (const float*)d_in[4];
  const float* Wr1 = (const float*)d_in[5];
  const float* Wl2 = (const float*)d_in[6];
  const float* bl2 = (const float*)d_in[7];
  const float* Wr2 = (const float*)d_in[8];
  const float* pw  = (const float*)d_in[9];
  const float* Wc1 = (const float*)d_in[10];
  const float* bc1 = (const float*)d_in[11];
  const float* Wc2 = (const float*)d_in[12];
  const float* bc2 = (const float*)d_in[13];
  float* out = (float*)d_out;

  char* ws = (char*)d_ws;                       // ~70 MB used
  float*    H1     = (float*)   (ws + 0);          // 32MB
  float*    H2     = (float*)   (ws + 33554432);   // 32MB
  uint32_t* rowptr = (uint32_t*)(ws + 67108864);   // 65537 u32 (pad 262400)
  int*      col    = (int*)     (ws + 67371264);   // 2MB
  float*    scores = (float*)   (ws + 69468416);   // 256KB
  unsigned short* Bpk = (unsigned short*)(ws + 69730560); // 256KB (2 layers)

  // one prep kernel: per-graph CSR (blocks 0..31) + weight pack (32..63)
  k_prep<<<64, 256, 0, stream>>>(esrc, edst, Wl1, Wr1, Wl2, Wr2,
                                 rowptr, col, Bpk);

  // fused layers: gather+mean+GEMM per block (round-6 structure + NT)
  k_sage<1><<<NT/32, 128, 0, stream>>>(x,  rowptr, col, Bpk,         bl1,
                                       H1, nullptr, nullptr);
  k_sage<2><<<NT/32, 128, 0, stream>>>(H1, rowptr, col, Bpk + 65536, bl2,
                                       H2, pw, scores);

  k_topk<<<NB, 1024, 0, stream>>>(scores, H2, Wc1, bc1, Wc2, bc2, out);
}